// Round 5
// baseline (464.611 us; speedup 1.0000x reference)
//
#include <hip/hip_runtime.h>
#include <hip/hip_bf16.h>
#include <cstdint>

// Problem constants (B=2,S=1024,D=1024; L=2,E=8,F=2048; k=2)
#define T_TOKENS 2048
#define DDIM 1024
#define FDIM 2048
#define NEXP 8
#define NLAYER 2
#define BMPAD 64           // per-expert row padding (= M tile)
#define RMAX 4608          // 2048*2 + 8*63 = 4537, rounded to 64-multiple

// A-operand tiles: 64 rows x 64 k, 4096 el (8 KB), order ((ksel*64+row)*8 + k&7),
//   ksel = (k>>5)*4 + ((k>>3)&3)  -- exactly MFMA fragment order.
// B-operand tiles: 128 cols x 64 k, 8192 el (16 KB), order ((ksel*128+col)*8 + k&7).
// Linear LDS copy of a tile is fragment-readable conflict-free (b128, 16 lanes x 16B).
#define ATILE_EL 4096
#define BTILE_EL 8192

typedef unsigned short u16;
typedef short bf16x8 __attribute__((ext_vector_type(8)));
typedef u16 u16x8 __attribute__((ext_vector_type(8)));
typedef u16 u16x4v __attribute__((ext_vector_type(4)));
typedef float f32x4 __attribute__((ext_vector_type(4)));

__device__ __forceinline__ u16 bf16_rn(float f) {
  unsigned u = __builtin_bit_cast(unsigned, f);
  u += 0x7fffu + ((u >> 16) & 1u);
  return (u16)(u >> 16);
}
__device__ __forceinline__ float bf16_f(u16 h) {
  unsigned u = ((unsigned)h) << 16;
  return __builtin_bit_cast(float, u);
}

__device__ __forceinline__ void gl16(const void* g, void* l) {
  __builtin_amdgcn_global_load_lds((const __attribute__((address_space(1))) void*)g,
                                   (__attribute__((address_space(3))) void*)l, 16, 0, 0);
}

// ---------------- routing ----------------
__global__ __launch_bounds__(256) void route_kernel(
    const float* __restrict__ x, const float* __restrict__ protos,
    int* __restrict__ eid, float* __restrict__ wgt) {
  const int t = blockIdx.x;
  const int tid = threadIdx.x;
  const float* xr = x + (size_t)t * DDIM;
  __shared__ float red[NEXP][256];
  float acc[NEXP];
#pragma unroll
  for (int e = 0; e < NEXP; ++e) acc[e] = 0.f;
  for (int d = tid; d < DDIM; d += 256) {
    float xv = xr[d];
#pragma unroll
    for (int e = 0; e < NEXP; ++e) acc[e] += xv * protos[e * DDIM + d];
  }
#pragma unroll
  for (int e = 0; e < NEXP; ++e) red[e][tid] = acc[e];
  __syncthreads();
  for (int s = 128; s > 0; s >>= 1) {
    if (tid < s) {
#pragma unroll
      for (int e = 0; e < NEXP; ++e) red[e][tid] += red[e][tid + s];
    }
    __syncthreads();
  }
  if (tid == 0) {
    float m1 = -1.f, m2 = -1.f;
    int i1 = 0, i2 = 0;
#pragma unroll
    for (int e = 0; e < NEXP; ++e) {
      float s = fabsf(red[e][0]);
      if (s > m1) { m2 = m1; i2 = i1; m1 = s; i1 = e; }
      else if (s > m2) { m2 = s; i2 = e; }
    }
    float e2 = __expf(m2 - m1);
    float z = 1.f + e2;
    eid[t * 2] = i1;
    eid[t * 2 + 1] = i2;
    wgt[t * 2] = 1.f / z;
    wgt[t * 2 + 1] = e2 / z;
  }
}

// ------------- compaction (padded to 64) -------------
__global__ __launch_bounds__(256) void compact_kernel(
    const int* __restrict__ eid, int* __restrict__ cnt, int* __restrict__ offp,
    int* __restrict__ row2token, int* __restrict__ pos) {
  __shared__ int lcnt[NEXP][256];
  __shared__ int s_off[NEXP], s_tot[NEXP];
  const int tid = threadIdx.x;
  const int base = tid * 16;

  int my[16];
#pragma unroll
  for (int i = 0; i < 4; ++i)
    *(int4*)&my[i * 4] = *(const int4*)(eid + base + i * 4);

#pragma unroll
  for (int e = 0; e < NEXP; ++e) {
    int c = 0;
#pragma unroll
    for (int i = 0; i < 16; ++i) c += (my[i] == e) ? 1 : 0;
    lcnt[e][tid] = c;
  }

  for (int r = tid; r < RMAX; r += 256) row2token[r] = -1;
  __syncthreads();

  if (tid < NEXP) {
    int run = 0;
    for (int i = 0; i < 256; ++i) {
      int v = lcnt[tid][i];
      lcnt[tid][i] = run;
      run += v;
    }
    s_tot[tid] = run;
  }
  __syncthreads();
  if (tid == 0) {
    int o = 0;
    for (int e = 0; e < NEXP; ++e) {
      s_off[e] = o;
      o += (s_tot[e] + BMPAD - 1) & ~(BMPAD - 1);
    }
  }
  __syncthreads();

  int myoff[NEXP];
#pragma unroll
  for (int e = 0; e < NEXP; ++e) myoff[e] = s_off[e] + lcnt[e][tid];
#pragma unroll
  for (int i = 0; i < 16; ++i) {
    int r = 0;
#pragma unroll
    for (int e = 0; e < NEXP; ++e) r = (my[i] == e) ? myoff[e] : r;
    row2token[r] = (base + i) >> 1;
    pos[base + i] = r;
#pragma unroll
    for (int e = 0; e < NEXP; ++e) myoff[e] += (my[i] == e) ? 1 : 0;
  }

  if (tid < NEXP) {
    cnt[tid] = s_tot[tid];
    offp[tid] = s_off[tid];
  }
}

// ------------- gather x rows -> bf16 hi/lo A-tiled buffers -------------
__global__ __launch_bounds__(256) void gather_kernel(
    const float* __restrict__ x, const int* __restrict__ row2token,
    u16* __restrict__ Ahi, u16* __restrict__ Alo) {
  const int r = blockIdx.x;
  const int t = row2token[r];
  const int c = threadIdx.x * 4;
  float4 v = make_float4(0.f, 0.f, 0.f, 0.f);
  if (t >= 0) v = *(const float4*)(x + (size_t)t * DDIM + c);
  float vv[4] = {v.x, v.y, v.z, v.w};
  u16x4v hi, lo;
#pragma unroll
  for (int i = 0; i < 4; ++i) {
    u16 h = bf16_rn(vv[i]);
    hi[i] = h;
    lo[i] = bf16_rn(vv[i] - bf16_f(h));
  }
  const int ksel = ((c >> 5) & 1) * 4 + ((c >> 3) & 3);
  const size_t el = ((size_t)(r >> 6) * (DDIM >> 6) + (c >> 6)) * ATILE_EL +
                    (size_t)(ksel * 64 + (r & 63)) * 8 + (c & 7);
  *(u16x4v*)(Ahi + el) = hi;
  *(u16x4v*)(Alo + el) = lo;
}

// ------------- W convert: f32 [e][K][N] -> bf16 hi(/lo) B-tiled [e][N/128][K/64] -------------
template <bool LO>
__global__ __launch_bounds__(256) void wconv_kernel(
    const float* __restrict__ W, u16* __restrict__ Hi, u16* __restrict__ Lo,
    int K, int N) {
  const int e = blockIdx.z, nb = blockIdx.x, kb = blockIdx.y;
  const float* Wp = W + ((size_t)e * K + (size_t)kb * 64) * N + nb * 128;
  __shared__ float tile[64][129];
  const int t = threadIdx.x;
#pragma unroll
  for (int i = 0; i < 8; ++i) {
    const int f4 = i * 256 + t;
    const int kr = f4 >> 5;
    const int c4 = (f4 & 31) * 4;
    float4 v = *(const float4*)(Wp + (size_t)kr * N + c4);
    *(float4*)&tile[kr][c4] = v;
  }
  __syncthreads();
  const size_t tb = ((size_t)e * (N >> 7) * (K >> 6) + (size_t)nb * (K >> 6) + kb) * BTILE_EL;
#pragma unroll
  for (int j = 0; j < 4; ++j) {
    const int cid = j * 256 + t;
    const int n = cid & 127, ksel = cid >> 7;
    const int kbase = (ksel >> 2) * 32 + (ksel & 3) * 8;
    u16x8 hv, lv;
#pragma unroll
    for (int i = 0; i < 8; ++i) {
      float f = tile[kbase + i][n];
      u16 h = bf16_rn(f);
      hv[i] = h;
      if (LO) lv[i] = bf16_rn(f - bf16_f(h));
    }
    *(u16x8*)(Hi + tb + (size_t)cid * 8) = hv;
    if (LO) *(u16x8*)(Lo + tb + (size_t)cid * 8) = lv;
  }
}

// ------------- grouped MFMA GEMM, phase-expanded split, 64x128 tiles -------------
// SPLIT: k-loop runs 3 phases {Ah*Bh, Ah*Bl, Al*Bh} through the SAME 24 KB LDS.
// SKF: split-K factor (blockIdx.z = e*SKF + sk); OUTMODE 0: f32 partial [sk][RMAX][N],
// 1: bf16 hi+lo A-tiled, 2: bf16 hi A-tiled.
template <bool RELU, bool SPLIT, int OUTMODE, int SKF>
__global__ __launch_bounds__(256, 4) void gemm_mfma(
    const u16* __restrict__ Ahi, const u16* __restrict__ Alo,
    const u16* __restrict__ Bhi, const u16* __restrict__ Blo,
    u16* __restrict__ OutHi, u16* __restrict__ OutLo, float* __restrict__ OutF,
    const int* __restrict__ cnt, const int* __restrict__ offp, int K, int N) {
  const int z = blockIdx.z;
  const int e = z / SKF, sk = z % SKF;
  const int cp = (cnt[e] + 63) & ~63;
  if ((int)(blockIdx.y * 64) >= cp) return;
  const int row0 = offp[e] + blockIdx.y * 64;
  const int n0 = blockIdx.x * 128;
  const int nkb = K >> 6;
  const int kbN = nkb / SKF;
  const int kb0 = sk * kbN;

  __shared__ u16 lds[ATILE_EL + BTILE_EL];  // 24 KB
  u16* As = lds;
  u16* Bs = lds + ATILE_EL;

  const int tid = threadIdx.x;
  const int lane = tid & 63;
  const int wid = tid >> 6;
  const int wr = wid >> 1, wc = wid & 1;     // 2x2 waves, 32x64 each
  const int lr = lane & 15, kg = lane >> 4;

  const int sgb = wid * 1024 + (lane << 4);  // global-side staging byte offset
  const int slb = wid * 1024;                // LDS-side (HW adds lane*16)

  f32x4 acc[2][4];
#pragma unroll
  for (int i = 0; i < 2; ++i)
#pragma unroll
    for (int j = 0; j < 4; ++j)
#pragma unroll
      for (int r = 0; r < 4; ++r) acc[i][j][r] = 0.f;

  const size_t abase = (size_t)(row0 >> 6) * nkb * ATILE_EL;
  const size_t bbase = ((size_t)e * (N >> 7) + (n0 >> 7)) * nkb * BTILE_EL;

  const int NPH = SPLIT ? 3 : 1;
  for (int ph = 0; ph < NPH; ++ph) {
    const u16* Ap = (SPLIT && ph == 2) ? Alo : Ahi;
    const u16* Bp = (SPLIT && ph == 1) ? Blo : Bhi;
    for (int kb = kb0; kb < kb0 + kbN; ++kb) {
      const char* ga = (const char*)(Ap + abase + (size_t)kb * ATILE_EL);
      const char* gb = (const char*)(Bp + bbase + (size_t)kb * BTILE_EL);
      gl16(ga + sgb, (char*)As + slb);
      gl16(ga + 4096 + sgb, (char*)As + 4096 + slb);
#pragma unroll
      for (int is = 0; is < 4; ++is)
        gl16(gb + (size_t)is * 4096 + sgb, (char*)Bs + is * 4096 + slb);
      __syncthreads();  // drains vmcnt(0): tiles staged

#pragma unroll
      for (int sub = 0; sub < 2; ++sub) {
        const int ksel = sub * 4 + kg;
        bf16x8 a0 = *(const bf16x8*)&As[(ksel * 64 + wr * 32 + lr) * 8];
        bf16x8 a1 = *(const bf16x8*)&As[(ksel * 64 + wr * 32 + 16 + lr) * 8];
        bf16x8 b0 = *(const bf16x8*)&Bs[(ksel * 128 + wc * 64 + lr) * 8];
        bf16x8 b1 = *(const bf16x8*)&Bs[(ksel * 128 + wc * 64 + 16 + lr) * 8];
        bf16x8 b2 = *(const bf16x8*)&Bs[(ksel * 128 + wc * 64 + 32 + lr) * 8];
        bf16x8 b3 = *(const bf16x8*)&Bs[(ksel * 128 + wc * 64 + 48 + lr) * 8];
        acc[0][0] = __builtin_amdgcn_mfma_f32_16x16x32_bf16(a0, b0, acc[0][0], 0, 0, 0);
        acc[0][1] = __builtin_amdgcn_mfma_f32_16x16x32_bf16(a0, b1, acc[0][1], 0, 0, 0);
        acc[0][2] = __builtin_amdgcn_mfma_f32_16x16x32_bf16(a0, b2, acc[0][2], 0, 0, 0);
        acc[0][3] = __builtin_amdgcn_mfma_f32_16x16x32_bf16(a0, b3, acc[0][3], 0, 0, 0);
        acc[1][0] = __builtin_amdgcn_mfma_f32_16x16x32_bf16(a1, b0, acc[1][0], 0, 0, 0);
        acc[1][1] = __builtin_amdgcn_mfma_f32_16x16x32_bf16(a1, b1, acc[1][1], 0, 0, 0);
        acc[1][2] = __builtin_amdgcn_mfma_f32_16x16x32_bf16(a1, b2, acc[1][2], 0, 0, 0);
        acc[1][3] = __builtin_amdgcn_mfma_f32_16x16x32_bf16(a1, b3, acc[1][3], 0, 0, 0);
      }
      __syncthreads();  // reads done before next stage overwrites
    }
  }

  // ---- epilogue: frag D: col=lr, row=kg*4+r ----
  const int nkbO = N >> 6;
#pragma unroll
  for (int i = 0; i < 2; ++i) {
#pragma unroll
    for (int j = 0; j < 4; ++j) {
      const int Cj = n0 + wc * 64 + j * 16 + lr;
      f32x4 v = acc[i][j];
#pragma unroll
      for (int r = 0; r < 4; ++r) {
        const int R = row0 + wr * 32 + i * 16 + kg * 4 + r;
        float f = v[r];
        if (RELU) f = fmaxf(f, 0.f);
        if constexpr (OUTMODE == 0) {
          OutF[((size_t)sk * RMAX + R) * N + Cj] = f;
        } else {
          const int ksel = ((Cj >> 5) & 1) * 4 + ((Cj >> 3) & 3);
          const size_t el = ((size_t)(R >> 6) * nkbO + (Cj >> 6)) * ATILE_EL +
                            (size_t)(ksel * 64 + (R & 63)) * 8 + (Cj & 7);
          u16 h = bf16_rn(f);
          OutHi[el] = h;
          if constexpr (OUTMODE == 1) OutLo[el] = bf16_rn(f - bf16_f(h));
        }
      }
    }
  }
}

// ------------- apply: x[t] += w0*(P0+P1)[pos0] + w1*(P0+P1)[pos1] -------------
__global__ __launch_bounds__(256) void apply_kernel(
    const float* __restrict__ part, const int* __restrict__ pos,
    const float* __restrict__ wgt, float* __restrict__ x) {
  const int t = blockIdx.x;
  const int c = threadIdx.x * 4;
  const int p0 = pos[t * 2], p1 = pos[t * 2 + 1];
  const float w0 = wgt[t * 2], w1 = wgt[t * 2 + 1];
  const float* P0 = part;
  const float* P1 = part + (size_t)RMAX * DDIM;
  float4 xa = *(float4*)(x + (size_t)t * DDIM + c);
  const float4 a0 = *(const float4*)(P0 + (size_t)p0 * DDIM + c);
  const float4 b0 = *(const float4*)(P1 + (size_t)p0 * DDIM + c);
  const float4 a1 = *(const float4*)(P0 + (size_t)p1 * DDIM + c);
  const float4 b1 = *(const float4*)(P1 + (size_t)p1 * DDIM + c);
  xa.x += w0 * (a0.x + b0.x) + w1 * (a1.x + b1.x);
  xa.y += w0 * (a0.y + b0.y) + w1 * (a1.y + b1.y);
  xa.z += w0 * (a0.z + b0.z) + w1 * (a1.z + b1.z);
  xa.w += w0 * (a0.w + b0.w) + w1 * (a1.w + b1.w);
  *(float4*)(x + (size_t)t * DDIM + c) = xa;
}

extern "C" void kernel_launch(void* const* d_in, const int* in_sizes, int n_in,
                              void* d_out, int out_size, void* d_ws, size_t ws_size,
                              hipStream_t stream) {
  const float* x = (const float*)d_in[0];
  const float* protos = (const float*)d_in[1];
  const float* W1 = (const float*)d_in[2];
  const float* W2 = (const float*)d_in[3];
  float* xcur = (float*)d_out;

  // ws (~162 MB): W_hi/W_lo 33.5 MB ea; Ag hi/lo 9.4 ea; h hi/lo 18.9 ea;
  // part (2x RMAX x D f32) 37.7; meta
  u16* W_hi = (u16*)d_ws;
  u16* W_lo = W_hi + (size_t)NEXP * DDIM * FDIM;
  u16* Ag_hi = W_lo + (size_t)NEXP * DDIM * FDIM;
  u16* Ag_lo = Ag_hi + (size_t)RMAX * DDIM;
  u16* h_hi = Ag_lo + (size_t)RMAX * DDIM;
  u16* h_lo = h_hi + (size_t)RMAX * FDIM;
  float* part = (float*)(h_lo + (size_t)RMAX * FDIM);
  float* wgt = part + (size_t)2 * RMAX * DDIM;
  int* eid = (int*)(wgt + T_TOKENS * 2);
  int* pos = eid + T_TOKENS * 2;
  int* cnt = pos + T_TOKENS * 2;
  int* offp = cnt + NEXP;
  int* row2token = offp + NEXP;

  hipMemcpyAsync(xcur, x, (size_t)T_TOKENS * DDIM * sizeof(float),
                 hipMemcpyDeviceToDevice, stream);

  for (int l = 0; l < NLAYER; ++l) {
    route_kernel<<<T_TOKENS, 256, 0, stream>>>(
        xcur, protos + (size_t)l * NEXP * DDIM, eid, wgt);
    compact_kernel<<<1, 256, 0, stream>>>(eid, cnt, offp, row2token, pos);
    gather_kernel<<<RMAX, 256, 0, stream>>>(xcur, row2token, Ag_hi, Ag_lo);
    const float* W1l = W1 + (size_t)l * NEXP * DDIM * FDIM;
    const float* W2l = W2 + (size_t)l * NEXP * FDIM * DDIM;
    if (l == 0) {
      // layer-1 output feeds layer-2 routing: split (3-phase) f32-grade GEMMs
      wconv_kernel<true><<<dim3(FDIM / 128, DDIM / 64, NEXP), 256, 0, stream>>>(
          W1l, W_hi, W_lo, DDIM, FDIM);
      gemm_mfma<true, true, 1, 1><<<dim3(FDIM / 128, 64, NEXP), 256, 0, stream>>>(
          Ag_hi, Ag_lo, W_hi, W_lo, h_hi, h_lo, nullptr, cnt, offp, DDIM, FDIM);
      wconv_kernel<true><<<dim3(DDIM / 128, FDIM / 64, NEXP), 256, 0, stream>>>(
          W2l, W_hi, W_lo, FDIM, DDIM);
      gemm_mfma<false, true, 0, 2><<<dim3(DDIM / 128, 64, NEXP * 2), 256, 0, stream>>>(
          h_hi, h_lo, W_hi, W_lo, nullptr, nullptr, part, cnt, offp, FDIM, DDIM);
    } else {
      // layer-2 output only feeds the final check: plain bf16
      wconv_kernel<false><<<dim3(FDIM / 128, DDIM / 64, NEXP), 256, 0, stream>>>(
          W1l, W_hi, nullptr, DDIM, FDIM);
      gemm_mfma<true, false, 2, 1><<<dim3(FDIM / 128, 64, NEXP), 256, 0, stream>>>(
          Ag_hi, nullptr, W_hi, nullptr, h_hi, nullptr, nullptr, cnt, offp, DDIM, FDIM);
      wconv_kernel<false><<<dim3(DDIM / 128, FDIM / 64, NEXP), 256, 0, stream>>>(
          W2l, W_hi, nullptr, FDIM, DDIM);
      gemm_mfma<false, false, 0, 2><<<dim3(DDIM / 128, 64, NEXP * 2), 256, 0, stream>>>(
          h_hi, nullptr, W_hi, nullptr, nullptr, nullptr, part, cnt, offp, FDIM, DDIM);
    }
    apply_kernel<<<T_TOKENS, 256, 0, stream>>>(part, pos, wgt, xcur);
  }
}

// Round 6
// 381.077 us; speedup vs baseline: 1.2192x; 1.2192x over previous
//
#include <hip/hip_runtime.h>
#include <hip/hip_bf16.h>
#include <cstdint>

// Problem constants (B=2,S=1024,D=1024; L=2,E=8,F=2048; k=2)
#define T_TOKENS 2048
#define DDIM 1024
#define FDIM 2048
#define NEXP 8
#define NLAYER 2
#define BMPAD 64           // per-expert row padding (= M tile)
#define RMAX 4608          // 2048*2 + 8*63 = 4537 -> 64-multiple

// A-operand tiles: 64 rows x 32 k, 2048 el (4 KB), order ((ksel*64+row)*8 + (k&7)),
//   ksel=(k>>3)&3 -- exactly MFMA fragment order for 16x16x32 bf16.
// B-operand tiles: 128 cols x 32 k, 4096 el (8 KB), order ((ksel*128+col)*8 + (k&7)).
// A linear LDS copy of a tile is fragment-readable conflict-free (b128, 16B x 16 lanes).
#define ATILE_EL 2048
#define BTILE_EL 4096

typedef unsigned short u16;
typedef short bf16x8 __attribute__((ext_vector_type(8)));
typedef u16 u16x8 __attribute__((ext_vector_type(8)));
typedef u16 u16x4v __attribute__((ext_vector_type(4)));
typedef float f32x4 __attribute__((ext_vector_type(4)));

__device__ __forceinline__ u16 bf16_rn(float f) {
  unsigned u = __builtin_bit_cast(unsigned, f);
  u += 0x7fffu + ((u >> 16) & 1u);
  return (u16)(u >> 16);
}
__device__ __forceinline__ float bf16_f(u16 h) {
  unsigned u = ((unsigned)h) << 16;
  return __builtin_bit_cast(float, u);
}

__device__ __forceinline__ void gl16(const void* g, void* l) {
  __builtin_amdgcn_global_load_lds((const __attribute__((address_space(1))) void*)g,
                                   (__attribute__((address_space(3))) void*)l, 16, 0, 0);
}

// ---------------- routing ----------------
__global__ __launch_bounds__(256) void route_kernel(
    const float* __restrict__ x, const float* __restrict__ protos,
    int* __restrict__ eid, float* __restrict__ wgt) {
  const int t = blockIdx.x;
  const int tid = threadIdx.x;
  const float* xr = x + (size_t)t * DDIM;
  __shared__ float red[NEXP][256];
  float acc[NEXP];
#pragma unroll
  for (int e = 0; e < NEXP; ++e) acc[e] = 0.f;
  for (int d = tid; d < DDIM; d += 256) {
    float xv = xr[d];
#pragma unroll
    for (int e = 0; e < NEXP; ++e) acc[e] += xv * protos[e * DDIM + d];
  }
#pragma unroll
  for (int e = 0; e < NEXP; ++e) red[e][tid] = acc[e];
  __syncthreads();
  for (int s = 128; s > 0; s >>= 1) {
    if (tid < s) {
#pragma unroll
      for (int e = 0; e < NEXP; ++e) red[e][tid] += red[e][tid + s];
    }
    __syncthreads();
  }
  if (tid == 0) {
    float m1 = -1.f, m2 = -1.f;
    int i1 = 0, i2 = 0;
#pragma unroll
    for (int e = 0; e < NEXP; ++e) {
      float s = fabsf(red[e][0]);
      if (s > m1) { m2 = m1; i2 = i1; m1 = s; i1 = e; }
      else if (s > m2) { m2 = s; i2 = e; }
    }
    float e2 = __expf(m2 - m1);
    float z = 1.f + e2;
    eid[t * 2] = i1;
    eid[t * 2 + 1] = i2;
    wgt[t * 2] = 1.f / z;
    wgt[t * 2 + 1] = e2 / z;
  }
}

// ------------- compaction (padded to 64) -------------
__global__ __launch_bounds__(256) void compact_kernel(
    const int* __restrict__ eid, int* __restrict__ cnt, int* __restrict__ offp,
    int* __restrict__ row2token, int* __restrict__ pos) {
  __shared__ int lcnt[NEXP][256];
  __shared__ int s_off[NEXP], s_tot[NEXP];
  const int tid = threadIdx.x;
  const int base = tid * 16;

  int my[16];
#pragma unroll
  for (int i = 0; i < 4; ++i)
    *(int4*)&my[i * 4] = *(const int4*)(eid + base + i * 4);

#pragma unroll
  for (int e = 0; e < NEXP; ++e) {
    int c = 0;
#pragma unroll
    for (int i = 0; i < 16; ++i) c += (my[i] == e) ? 1 : 0;
    lcnt[e][tid] = c;
  }

  for (int r = tid; r < RMAX; r += 256) row2token[r] = -1;
  __syncthreads();

  if (tid < NEXP) {
    int run = 0;
    for (int i = 0; i < 256; ++i) {
      int v = lcnt[tid][i];
      lcnt[tid][i] = run;
      run += v;
    }
    s_tot[tid] = run;
  }
  __syncthreads();
  if (tid == 0) {
    int o = 0;
    for (int e = 0; e < NEXP; ++e) {
      s_off[e] = o;
      o += (s_tot[e] + BMPAD - 1) & ~(BMPAD - 1);
    }
  }
  __syncthreads();

  int myoff[NEXP];
#pragma unroll
  for (int e = 0; e < NEXP; ++e) myoff[e] = s_off[e] + lcnt[e][tid];
#pragma unroll
  for (int i = 0; i < 16; ++i) {
    int r = 0;
#pragma unroll
    for (int e = 0; e < NEXP; ++e) r = (my[i] == e) ? myoff[e] : r;
    row2token[r] = (base + i) >> 1;
    pos[base + i] = r;
#pragma unroll
    for (int e = 0; e < NEXP; ++e) myoff[e] += (my[i] == e) ? 1 : 0;
  }

  if (tid < NEXP) {
    cnt[tid] = s_tot[tid];
    offp[tid] = s_off[tid];
  }
}

// ------------- gather x rows -> bf16 hi/lo A-tiled buffers -------------
__global__ __launch_bounds__(256) void gather_kernel(
    const float* __restrict__ x, const int* __restrict__ row2token,
    u16* __restrict__ Ahi, u16* __restrict__ Alo) {
  const int r = blockIdx.x;
  const int t = row2token[r];
  const int c = threadIdx.x * 4;
  float4 v = make_float4(0.f, 0.f, 0.f, 0.f);
  if (t >= 0) v = *(const float4*)(x + (size_t)t * DDIM + c);
  float vv[4] = {v.x, v.y, v.z, v.w};
  u16x4v hi, lo;
#pragma unroll
  for (int i = 0; i < 4; ++i) {
    u16 h = bf16_rn(vv[i]);
    hi[i] = h;
    lo[i] = bf16_rn(vv[i] - bf16_f(h));
  }
  const size_t el = ((size_t)(r >> 6) * (DDIM >> 5) + (c >> 5)) * ATILE_EL +
                    (size_t)(((c >> 3) & 3) * 64 + (r & 63)) * 8 + (c & 7);
  *(u16x4v*)(Ahi + el) = hi;
  *(u16x4v*)(Alo + el) = lo;
}

// ------------- W convert: f32 [e][K][N] -> bf16 hi(/lo) B-tiled [e][N/128][K/32] -------------
template <bool LO>
__global__ __launch_bounds__(256) void wconv_kernel(
    const float* __restrict__ W, u16* __restrict__ Hi, u16* __restrict__ Lo,
    int K, int N) {
  const int e = blockIdx.z, nb = blockIdx.x, kb = blockIdx.y;
  const float* Wp = W + ((size_t)e * K + (size_t)kb * 32) * N + nb * 128;
  __shared__ float tile[32][129];
  const int t = threadIdx.x;
#pragma unroll
  for (int i = 0; i < 4; ++i) {
    const int f4 = i * 256 + t;        // 1024 float4 = 32 rows x 32 f4
    const int kr = f4 >> 5;
    const int c4 = (f4 & 31) * 4;
    float4 v = *(const float4*)(Wp + (size_t)kr * N + c4);
    *(float4*)&tile[kr][c4] = v;
  }
  __syncthreads();
  const size_t tb = (((size_t)e * (N >> 7) + nb) * (K >> 5) + kb) * BTILE_EL;
#pragma unroll
  for (int j = 0; j < 2; ++j) {
    const int cid = j * 256 + t;       // 512 chunks of 8
    const int n = cid & 127, ksel = cid >> 7;
    u16x8 hv, lv;
#pragma unroll
    for (int i = 0; i < 8; ++i) {
      float f = tile[ksel * 8 + i][n];
      u16 h = bf16_rn(f);
      hv[i] = h;
      if (LO) lv[i] = bf16_rn(f - bf16_f(h));
    }
    *(u16x8*)(Hi + tb + (size_t)cid * 8) = hv;
    if (LO) *(u16x8*)(Lo + tb + (size_t)cid * 8) = lv;
  }
}

// ------------- grouped MFMA GEMM: fused split, 64x128 tile, BK=32, double-buffered -------------
// SPLIT: per staged tile, apply Ah*Bh + Ah*Bl + Al*Bh (one pass over K).
// OUTMODE 0: f32 row-major; 1: bf16 hi+lo A-tiled; 2: bf16 hi A-tiled.
template <bool RELU, bool SPLIT, int OUTMODE>
__global__ __launch_bounds__(256, SPLIT ? 3 : 4) void gemm_mfma(
    const u16* __restrict__ Ahi, const u16* __restrict__ Alo,
    const u16* __restrict__ Bhi, const u16* __restrict__ Blo,
    u16* __restrict__ OutHi, u16* __restrict__ OutLo, float* __restrict__ OutF,
    const int* __restrict__ cnt, const int* __restrict__ offp, int K, int N) {
  const int e = blockIdx.z;
  const int cp = (cnt[e] + 63) & ~63;
  if ((int)(blockIdx.y * 64) >= cp) return;
  const int row0 = offp[e] + blockIdx.y * 64;
  const int n0 = blockIdx.x * 128;
  const int nkb = K >> 5;

  constexpr int BUF_EL = SPLIT ? 12288 : 6144;  // [AsH|AsL|BsH|BsL] / [AsH|BsH]
  __shared__ u16 lds[2 * BUF_EL];

  const int tid = threadIdx.x;
  const int lane = tid & 63;
  const int wid = tid >> 6;
  const int wr = wid >> 1, wc = wid & 1;     // 2x2 waves, 32x64 each
  const int lr = lane & 15, kg = lane >> 4;
  const int lo16 = lane << 4;

  f32x4 acc[2][4];
#pragma unroll
  for (int i = 0; i < 2; ++i)
#pragma unroll
    for (int j = 0; j < 4; ++j)
#pragma unroll
      for (int r = 0; r < 4; ++r) acc[i][j][r] = 0.f;

  const size_t abase = (size_t)(row0 >> 6) * nkb * ATILE_EL;
  const size_t bbase = ((size_t)e * (N >> 7) + (n0 >> 7)) * nkb * BTILE_EL;

  // ---- staging: one operand per wave, next tile into buf b ----
  auto STAGE = [&](int kb, int b) {
    char* d = (char*)(lds + b * BUF_EL);
    const char* gah = (const char*)(Ahi + abase + (size_t)kb * ATILE_EL);
    const char* gbh = (const char*)(Bhi + bbase + (size_t)kb * BTILE_EL);
    if constexpr (SPLIT) {
      const char* gal = (const char*)(Alo + abase + (size_t)kb * ATILE_EL);
      const char* gbl = (const char*)(Blo + bbase + (size_t)kb * BTILE_EL);
      if (wid == 0) {
#pragma unroll
        for (int i = 0; i < 4; ++i) gl16(gah + i * 1024 + lo16, d + i * 1024);
#pragma unroll
        for (int i = 0; i < 4; ++i) gl16(gal + i * 1024 + lo16, d + 4096 + i * 1024);
      } else if (wid == 1) {
#pragma unroll
        for (int i = 0; i < 8; ++i) gl16(gbh + i * 1024 + lo16, d + 8192 + i * 1024);
      } else if (wid == 2) {
#pragma unroll
        for (int i = 0; i < 8; ++i) gl16(gbl + i * 1024 + lo16, d + 16384 + i * 1024);
      }
    } else {
      if (wid == 0) {
#pragma unroll
        for (int i = 0; i < 4; ++i) gl16(gah + i * 1024 + lo16, d + i * 1024);
      } else if (wid == 1) {
#pragma unroll
        for (int i = 0; i < 4; ++i) gl16(gbh + i * 1024 + lo16, d + 4096 + i * 1024);
      } else if (wid == 2) {
#pragma unroll
        for (int i = 0; i < 4; ++i) gl16(gbh + 4096 + i * 1024 + lo16, d + 8192 + i * 1024);
      }
    }
  };

  STAGE(0, 0);
  __syncthreads();  // vmcnt(0): buf0 ready

  int cur = 0;
  for (int kb = 0; kb < nkb; ++kb) {
    if (kb + 1 < nkb) STAGE(kb + 1, cur ^ 1);  // prefetch overlaps compute below

    const u16* buf = lds + cur * BUF_EL;
    const u16* AsH = buf;
    const u16* BsH = buf + (SPLIT ? 4096 : 2048);
    bf16x8 ah0 = *(const bf16x8*)&AsH[(kg * 64 + wr * 32 + lr) * 8];
    bf16x8 ah1 = *(const bf16x8*)&AsH[(kg * 64 + wr * 32 + 16 + lr) * 8];
    bf16x8 bh[4];
#pragma unroll
    for (int j = 0; j < 4; ++j)
      bh[j] = *(const bf16x8*)&BsH[(kg * 128 + wc * 64 + j * 16 + lr) * 8];
#pragma unroll
    for (int j = 0; j < 4; ++j) {
      acc[0][j] = __builtin_amdgcn_mfma_f32_16x16x32_bf16(ah0, bh[j], acc[0][j], 0, 0, 0);
      acc[1][j] = __builtin_amdgcn_mfma_f32_16x16x32_bf16(ah1, bh[j], acc[1][j], 0, 0, 0);
    }
    if constexpr (SPLIT) {
      const u16* AsL = buf + 2048;
      const u16* BsL = buf + 8192;
      bf16x8 al0 = *(const bf16x8*)&AsL[(kg * 64 + wr * 32 + lr) * 8];
      bf16x8 al1 = *(const bf16x8*)&AsL[(kg * 64 + wr * 32 + 16 + lr) * 8];
#pragma unroll
      for (int j = 0; j < 4; ++j) {
        bf16x8 bl = *(const bf16x8*)&BsL[(kg * 128 + wc * 64 + j * 16 + lr) * 8];
        acc[0][j] = __builtin_amdgcn_mfma_f32_16x16x32_bf16(ah0, bl, acc[0][j], 0, 0, 0);
        acc[1][j] = __builtin_amdgcn_mfma_f32_16x16x32_bf16(ah1, bl, acc[1][j], 0, 0, 0);
        acc[0][j] = __builtin_amdgcn_mfma_f32_16x16x32_bf16(al0, bh[j], acc[0][j], 0, 0, 0);
        acc[1][j] = __builtin_amdgcn_mfma_f32_16x16x32_bf16(al1, bh[j], acc[1][j], 0, 0, 0);
      }
    }
    __syncthreads();  // drains vmcnt(0) -> prefetch landed; all reads of buf done
    cur ^= 1;
  }

  // ---- epilogue: frag D: col=lr, row=kg*4+r ----
  const int nkbO = N >> 5;
#pragma unroll
  for (int i = 0; i < 2; ++i) {
#pragma unroll
    for (int j = 0; j < 4; ++j) {
      const int Cj = n0 + wc * 64 + j * 16 + lr;
      f32x4 v = acc[i][j];
#pragma unroll
      for (int r = 0; r < 4; ++r) {
        const int R = row0 + wr * 32 + i * 16 + kg * 4 + r;
        float f = v[r];
        if (RELU) f = fmaxf(f, 0.f);
        if constexpr (OUTMODE == 0) {
          OutF[(size_t)R * N + Cj] = f;
        } else {
          const size_t el = ((size_t)(R >> 6) * nkbO + (Cj >> 5)) * ATILE_EL +
                            (size_t)(((Cj >> 3) & 3) * 64 + (R & 63)) * 8 + (Cj & 7);
          u16 h = bf16_rn(f);
          OutHi[el] = h;
          if constexpr (OUTMODE == 1) OutLo[el] = bf16_rn(f - bf16_f(h));
        }
      }
    }
  }
}

// ------------- apply: x[t] += w0*y[pos0] + w1*y[pos1] -------------
__global__ __launch_bounds__(256) void apply_kernel(
    const float* __restrict__ ytmp, const int* __restrict__ pos,
    const float* __restrict__ wgt, float* __restrict__ x) {
  const int t = blockIdx.x;
  const int c = threadIdx.x * 4;
  const int p0 = pos[t * 2], p1 = pos[t * 2 + 1];
  const float w0 = wgt[t * 2], w1 = wgt[t * 2 + 1];
  float4 xa = *(float4*)(x + (size_t)t * DDIM + c);
  const float4 y0 = *(const float4*)(ytmp + (size_t)p0 * DDIM + c);
  const float4 y1 = *(const float4*)(ytmp + (size_t)p1 * DDIM + c);
  xa.x += w0 * y0.x + w1 * y1.x;
  xa.y += w0 * y0.y + w1 * y1.y;
  xa.z += w0 * y0.z + w1 * y1.z;
  xa.w += w0 * y0.w + w1 * y1.w;
  *(float4*)(x + (size_t)t * DDIM + c) = xa;
}

extern "C" void kernel_launch(void* const* d_in, const int* in_sizes, int n_in,
                              void* d_out, int out_size, void* d_ws, size_t ws_size,
                              hipStream_t stream) {
  const float* x = (const float*)d_in[0];
  const float* protos = (const float*)d_in[1];
  const float* W1 = (const float*)d_in[2];
  const float* W2 = (const float*)d_in[3];
  float* xcur = (float*)d_out;

  // ws (~142 MB): W hi/lo 33.5 ea; Ag hi/lo 9.4 ea; h hi/lo 18.9 ea; ytmp 18.9; meta
  u16* W_hi = (u16*)d_ws;
  u16* W_lo = W_hi + (size_t)NEXP * DDIM * FDIM;
  u16* Ag_hi = W_lo + (size_t)NEXP * DDIM * FDIM;
  u16* Ag_lo = Ag_hi + (size_t)RMAX * DDIM;
  u16* h_hi = Ag_lo + (size_t)RMAX * DDIM;
  u16* h_lo = h_hi + (size_t)RMAX * FDIM;
  float* ytmp = (float*)(h_lo + (size_t)RMAX * FDIM);
  float* wgt = ytmp + (size_t)RMAX * DDIM;
  int* eid = (int*)(wgt + T_TOKENS * 2);
  int* pos = eid + T_TOKENS * 2;
  int* cnt = pos + T_TOKENS * 2;
  int* offp = cnt + NEXP;
  int* row2token = offp + NEXP;

  hipMemcpyAsync(xcur, x, (size_t)T_TOKENS * DDIM * sizeof(float),
                 hipMemcpyDeviceToDevice, stream);

  for (int l = 0; l < NLAYER; ++l) {
    route_kernel<<<T_TOKENS, 256, 0, stream>>>(
        xcur, protos + (size_t)l * NEXP * DDIM, eid, wgt);
    compact_kernel<<<1, 256, 0, stream>>>(eid, cnt, offp, row2token, pos);
    gather_kernel<<<RMAX, 256, 0, stream>>>(xcur, row2token, Ag_hi, Ag_lo);
    const float* W1l = W1 + (size_t)l * NEXP * DDIM * FDIM;
    const float* W2l = W2 + (size_t)l * NEXP * FDIM * DDIM;
    if (l == 0) {
      // layer-1 output feeds layer-2 routing: fused-split (f32-grade) GEMMs
      wconv_kernel<true><<<dim3(FDIM / 128, DDIM / 32, NEXP), 256, 0, stream>>>(
          W1l, W_hi, W_lo, DDIM, FDIM);
      gemm_mfma<true, true, 1><<<dim3(FDIM / 128, RMAX / 64, NEXP), 256, 0, stream>>>(
          Ag_hi, Ag_lo, W_hi, W_lo, h_hi, h_lo, nullptr, cnt, offp, DDIM, FDIM);
      wconv_kernel<true><<<dim3(DDIM / 128, FDIM / 32, NEXP), 256, 0, stream>>>(
          W2l, W_hi, W_lo, FDIM, DDIM);
      gemm_mfma<false, true, 0><<<dim3(DDIM / 128, RMAX / 64, NEXP), 256, 0, stream>>>(
          h_hi, h_lo, W_hi, W_lo, nullptr, nullptr, ytmp, cnt, offp, FDIM, DDIM);
    } else {
      // layer-2 output only feeds the final check: plain bf16
      wconv_kernel<false><<<dim3(FDIM / 128, DDIM / 32, NEXP), 256, 0, stream>>>(
          W1l, W_hi, nullptr, DDIM, FDIM);
      gemm_mfma<true, false, 2><<<dim3(FDIM / 128, RMAX / 64, NEXP), 256, 0, stream>>>(
          Ag_hi, nullptr, W_hi, nullptr, h_hi, nullptr, nullptr, cnt, offp, DDIM, FDIM);
      wconv_kernel<false><<<dim3(DDIM / 128, FDIM / 32, NEXP), 256, 0, stream>>>(
          W2l, W_hi, nullptr, FDIM, DDIM);
      gemm_mfma<false, false, 0><<<dim3(DDIM / 128, RMAX / 64, NEXP), 256, 0, stream>>>(
          h_hi, nullptr, W_hi, nullptr, nullptr, nullptr, ytmp, cnt, offp, FDIM, DDIM);
    }
    apply_kernel<<<T_TOKENS, 256, 0, stream>>>(ytmp, pos, wgt, xcur);
  }
}